// Round 3
// baseline (626.346 us; speedup 1.0000x reference)
//
#include <hip/hip_runtime.h>

#define H 1024
#define DFF 2048
#define NE 8
#define NT 2048            // B*S tokens
#define NPAIR (NT * 2)     // TOPK=2

typedef __bf16 bf16;
typedef __bf16 bf16x8 __attribute__((ext_vector_type(8)));
typedef __bf16 bf16x4 __attribute__((ext_vector_type(4)));
typedef float f32x4 __attribute__((ext_vector_type(4)));

__device__ __forceinline__ void async_copy16(const void* g, void* l) {
  __builtin_amdgcn_global_load_lds(
      (const __attribute__((address_space(1))) unsigned int*)g,
      (__attribute__((address_space(3))) unsigned int*)l, 16, 0, 0);
}

// ---------------- gate: logits -> top2 -> softmax, + x f32->bf16 ----------------
__global__ __launch_bounds__(64) void gate_kernel(
    const float* __restrict__ x, const float* __restrict__ gw,
    const float* __restrict__ gb, int* __restrict__ cnt,
    int* __restrict__ topi, float* __restrict__ topw,
    bf16* __restrict__ xb) {
  int t = blockIdx.x;
  int lane = threadIdx.x;
  const float* xr = x + (size_t)t * H;
  bf16* xbr = xb + (size_t)t * H;
  // fused x conversion (vectorized)
#pragma unroll
  for (int it = 0; it < 4; ++it) {
    int i = it * 256 + lane * 4;
    float4 v = *(const float4*)(xr + i);
    bf16x4 o = {(bf16)v.x, (bf16)v.y, (bf16)v.z, (bf16)v.w};
    *(bf16x4*)(xbr + i) = o;
  }
  float acc[NE];
#pragma unroll
  for (int e = 0; e < NE; ++e) acc[e] = 0.f;
  for (int i = lane; i < H; i += 64) {
    float xv = xr[i];
    const float* g = gw + (size_t)i * NE;
#pragma unroll
    for (int e = 0; e < NE; ++e) acc[e] += xv * g[e];
  }
#pragma unroll
  for (int e = 0; e < NE; ++e) {
    for (int off = 32; off > 0; off >>= 1)
      acc[e] += __shfl_down(acc[e], off, 64);
  }
  if (lane == 0) {
    float v[NE];
#pragma unroll
    for (int e = 0; e < NE; ++e) v[e] = acc[e] + gb[e];
    int i1 = 0;
#pragma unroll
    for (int e = 1; e < NE; ++e) if (v[e] > v[i1]) i1 = e;     // lowest index on ties (jax top_k)
    int i2 = (i1 == 0) ? 1 : 0;
#pragma unroll
    for (int e = 0; e < NE; ++e) if (e != i1 && v[e] > v[i2]) i2 = e;
    float d = expf(v[i2] - v[i1]);       // <= 1
    float p1 = 1.f / (1.f + d);
    float p2 = d * p1;
    topi[2 * t] = i1; topi[2 * t + 1] = i2;
    topw[2 * t] = p1; topw[2 * t + 1] = p2;
    atomicAdd(&cnt[i1], 1);
    atomicAdd(&cnt[i2], 1);
  }
}

__global__ void prefix_kernel(const int* __restrict__ cnt, int* __restrict__ off) {
  if (threadIdx.x == 0 && blockIdx.x == 0) {
    int s = 0;
    for (int e = 0; e < NE; ++e) { off[e] = s; s += cnt[e]; }
    off[NE] = s;
  }
}

__global__ __launch_bounds__(256) void scatter_kernel(
    const int* __restrict__ topi, int* __restrict__ cnt2,
    const int* __restrict__ off, int* __restrict__ pair_tok,
    int* __restrict__ pair_pos) {
  int t = blockIdx.x * 256 + threadIdx.x;
  if (t >= NT) return;
#pragma unroll
  for (int k = 0; k < 2; ++k) {
    int e = topi[2 * t + k];
    int idx = atomicAdd(&cnt2[e], 1);
    int pos = off[e] + idx;
    pair_tok[pos] = t;
    pair_pos[2 * t + k] = pos;
  }
}

// ---------------- merged transpose+convert: [E][K][N] f32 -> [E][N][K] bf16 ----------------
// f32 LDS tile, pad 65 words: store bank=(n+k)%32 (2-way), read bank=(n+k8+j)%32 (2-way)
__global__ __launch_bounds__(256) void tconv_kernel(
    const float* __restrict__ w1, const float* __restrict__ w2,
    const float* __restrict__ wg, const float* __restrict__ w3,
    bf16* __restrict__ w1t, bf16* __restrict__ w2t,
    bf16* __restrict__ wgt, bf16* __restrict__ w3t) {
  int bid = blockIdx.x;
  const float* src; bf16* dst; int K, N, e, kt, nt;
  if (bid < 8192) {                      // w1 / w2 : K=H, N=DFF, 512 tiles/expert
    if (bid < 4096) { src = w1; dst = w1t; } else { src = w2; dst = w2t; bid -= 4096; }
    K = H; N = DFF;
    e = bid >> 9; int l = bid & 511; kt = l >> 5; nt = l & 31;
  } else if (bid < 16384) {              // wg : K=DFF, N=DFF, 1024 tiles/expert
    src = wg; dst = wgt; K = DFF; N = DFF;
    int l = bid - 8192; e = l >> 10; l &= 1023; kt = l >> 5; nt = l & 31;
  } else {                               // w3 : K=DFF, N=H, 512 tiles/expert
    src = w3; dst = w3t; K = DFF; N = H;
    int l = bid - 16384; e = l >> 9; l &= 511; kt = l >> 4; nt = l & 15;
  }
  src += ((size_t)e * K + kt * 64) * N + nt * 64;
  dst += ((size_t)e * N + nt * 64) * K + kt * 64;

  __shared__ float T[64 * 65];
  int t = threadIdx.x;
  int n4 = (t & 15) * 4, kk = t >> 4;
#pragma unroll
  for (int it = 0; it < 4; ++it) {
    int k = it * 16 + kk;
    float4 v = *(const float4*)(src + (size_t)k * N + n4);
    T[(n4 + 0) * 65 + k] = v.x;
    T[(n4 + 1) * 65 + k] = v.y;
    T[(n4 + 2) * 65 + k] = v.z;
    T[(n4 + 3) * 65 + k] = v.w;
  }
  __syncthreads();
  int k8 = (t & 7) * 8, n = t >> 3;
#pragma unroll
  for (int it = 0; it < 2; ++it) {
    int nn = it * 32 + n;
    const float* row = &T[nn * 65 + k8];
    bf16x8 o = {(bf16)row[0], (bf16)row[1], (bf16)row[2], (bf16)row[3],
                (bf16)row[4], (bf16)row[5], (bf16)row[6], (bf16)row[7]};
    *(bf16x8*)(dst + (size_t)nn * K + k8) = o;
  }
}

// ======== GEMM kernels: BK=64 (128 bytes), XOR-8 swizzle, global_load_lds ========
// LDS layout: row r (128B) at offset r*128; 16B chunk c of row r stored at slot c^(r&7).
// Staging: lane l (lr=l>>3, lc=l&7) of copy j fetches row (32w+8j+lr), global chunk lc^lr.
// Frag read: slot = (ksub*4+quad)^(l16&7) -> conflict-free per 8-lane phase.

// ---------------- stage 1: Z = (x@w1+b1)*(x@w2+b2)  [128m x 64n, dual B] ----------------
__global__ __launch_bounds__(256) void ffn1_kernel(
    const bf16* __restrict__ xb, const bf16* __restrict__ w1t,
    const float* __restrict__ b1, const bf16* __restrict__ w2t,
    const float* __restrict__ b2, const int* __restrict__ off,
    const int* __restrict__ pair_tok, bf16* __restrict__ Z) {
  int e = blockIdx.y;
  int base = off[e];
  int count = off[e + 1] - base;
  int m0 = blockIdx.z * 128;
  if (m0 >= count) return;
  int n0 = blockIdx.x * 64;

  __shared__ __align__(16) bf16 As[128 * 64];   // 16 KB
  __shared__ __align__(16) bf16 B1s[64 * 64];   // 8 KB
  __shared__ __align__(16) bf16 B2s[64 * 64];   // 8 KB

  int tid = threadIdx.x;
  int wave = tid >> 6, lane = tid & 63;
  int quad = lane >> 4, l16 = lane & 15;
  int wm = wave & 1, wn = wave >> 1;
  int lr = lane >> 3, lc = lane & 7;
  int cg = (lc ^ lr) * 16;

  const char* apj[4];
#pragma unroll
  for (int j = 0; j < 4; ++j) {
    int r = m0 + wave * 32 + j * 8 + lr;
    if (r >= count) r = count - 1;
    apj[j] = (const char*)(xb + (size_t)pair_tok[base + r] * H) + cg;
  }
  const char* w1e = (const char*)(w1t + (size_t)e * DFF * H);
  const char* w2e = (const char*)(w2t + (size_t)e * DFF * H);
  const char* b1pj[2];
  const char* b2pj[2];
#pragma unroll
  for (int j = 0; j < 2; ++j) {
    int r = n0 + wave * 16 + j * 8 + lr;
    b1pj[j] = w1e + (size_t)r * (H * 2) + cg;
    b2pj[j] = w2e + (size_t)r * (H * 2) + cg;
  }

  char* asd  = (char*)As  + wave * 4096;
  char* b1sd = (char*)B1s + wave * 2048;
  char* b2sd = (char*)B2s + wave * 2048;

  int slot0 = ((0 + quad) ^ (l16 & 7)) * 16;
  int slot1 = ((4 + quad) ^ (l16 & 7)) * 16;
  const char* arp  = (const char*)As  + (wm * 64 + l16) * 128;
  const char* b1rp = (const char*)B1s + (wn * 32 + l16) * 128;
  const char* b2rp = (const char*)B2s + (wn * 32 + l16) * 128;

  f32x4 acc1[4][2] = {};
  f32x4 acc2[4][2] = {};

  for (int k0 = 0; k0 < H * 2; k0 += 128) {
#pragma unroll
    for (int j = 0; j < 4; ++j) async_copy16(apj[j] + k0, asd + j * 1024);
#pragma unroll
    for (int j = 0; j < 2; ++j) async_copy16(b1pj[j] + k0, b1sd + j * 1024);
#pragma unroll
    for (int j = 0; j < 2; ++j) async_copy16(b2pj[j] + k0, b2sd + j * 1024);
    __syncthreads();
#pragma unroll
    for (int ks = 0; ks < 2; ++ks) {
      int slot = ks ? slot1 : slot0;
      bf16x8 af[4], bf1[2], bf2[2];
#pragma unroll
      for (int i = 0; i < 4; ++i) af[i] = *(const bf16x8*)(arp + i * 2048 + slot);
#pragma unroll
      for (int i = 0; i < 2; ++i) bf1[i] = *(const bf16x8*)(b1rp + i * 2048 + slot);
#pragma unroll
      for (int i = 0; i < 2; ++i) bf2[i] = *(const bf16x8*)(b2rp + i * 2048 + slot);
#pragma unroll
      for (int fm = 0; fm < 4; ++fm)
#pragma unroll
        for (int fn = 0; fn < 2; ++fn) {
          acc1[fm][fn] = __builtin_amdgcn_mfma_f32_16x16x32_bf16(af[fm], bf1[fn], acc1[fm][fn], 0, 0, 0);
          acc2[fm][fn] = __builtin_amdgcn_mfma_f32_16x16x32_bf16(af[fm], bf2[fn], acc2[fm][fn], 0, 0, 0);
        }
    }
    __syncthreads();
  }

  int mb = m0 + wm * 64;
#pragma unroll
  for (int fm = 0; fm < 4; ++fm) {
#pragma unroll
    for (int fn = 0; fn < 2; ++fn) {
      int n = n0 + wn * 32 + fn * 16 + l16;
      float bb1 = b1[e * DFF + n];
      float bb2 = b2[e * DFF + n];
#pragma unroll
      for (int r = 0; r < 4; ++r) {
        int m = mb + fm * 16 + quad * 4 + r;
        if (m < count) {
          float zv = (acc1[fm][fn][r] + bb1) * (acc2[fm][fn][r] + bb2);
          Z[(size_t)(base + m) * DFF + n] = (bf16)zv;
        }
      }
    }
  }
}

// ---------------- stage 2: S = silu(Z@wg + bg)  [128m x 128n] ----------------
__global__ __launch_bounds__(256) void ffn2_kernel(
    const bf16* __restrict__ Z, const bf16* __restrict__ wgt,
    const float* __restrict__ bg, const int* __restrict__ off,
    bf16* __restrict__ S) {
  int e = blockIdx.y;
  int base = off[e];
  int count = off[e + 1] - base;
  int m0 = blockIdx.z * 128;
  if (m0 >= count) return;
  int n0 = blockIdx.x * 128;

  __shared__ __align__(16) bf16 As[128 * 64];   // 16 KB
  __shared__ __align__(16) bf16 Bs[128 * 64];   // 16 KB

  int tid = threadIdx.x;
  int wave = tid >> 6, lane = tid & 63;
  int quad = lane >> 4, l16 = lane & 15;
  int wm = wave & 1, wn = wave >> 1;
  int lr = lane >> 3, lc = lane & 7;
  int cg = (lc ^ lr) * 16;

  const char* apj[4];
  const char* bpj[4];
  const char* we = (const char*)(wgt + (size_t)e * DFF * DFF);
#pragma unroll
  for (int j = 0; j < 4; ++j) {
    int r = m0 + wave * 32 + j * 8 + lr;
    if (r >= count) r = count - 1;
    apj[j] = (const char*)(Z + (size_t)(base + r) * DFF) + cg;
    int rb = n0 + wave * 32 + j * 8 + lr;
    bpj[j] = we + (size_t)rb * (DFF * 2) + cg;
  }

  char* asd = (char*)As + wave * 4096;
  char* bsd = (char*)Bs + wave * 4096;

  int slot0 = ((0 + quad) ^ (l16 & 7)) * 16;
  int slot1 = ((4 + quad) ^ (l16 & 7)) * 16;
  const char* arp = (const char*)As + (wm * 64 + l16) * 128;
  const char* brp = (const char*)Bs + (wn * 64 + l16) * 128;

  f32x4 acc[4][4] = {};

  for (int k0 = 0; k0 < DFF * 2; k0 += 128) {
#pragma unroll
    for (int j = 0; j < 4; ++j) async_copy16(apj[j] + k0, asd + j * 1024);
#pragma unroll
    for (int j = 0; j < 4; ++j) async_copy16(bpj[j] + k0, bsd + j * 1024);
    __syncthreads();
#pragma unroll
    for (int ks = 0; ks < 2; ++ks) {
      int slot = ks ? slot1 : slot0;
      bf16x8 af[4], bfr[4];
#pragma unroll
      for (int i = 0; i < 4; ++i) af[i] = *(const bf16x8*)(arp + i * 2048 + slot);
#pragma unroll
      for (int i = 0; i < 4; ++i) bfr[i] = *(const bf16x8*)(brp + i * 2048 + slot);
#pragma unroll
      for (int fm = 0; fm < 4; ++fm)
#pragma unroll
        for (int fn = 0; fn < 4; ++fn)
          acc[fm][fn] = __builtin_amdgcn_mfma_f32_16x16x32_bf16(af[fm], bfr[fn], acc[fm][fn], 0, 0, 0);
    }
    __syncthreads();
  }

  int mb = m0 + wm * 64;
#pragma unroll
  for (int fm = 0; fm < 4; ++fm) {
#pragma unroll
    for (int fn = 0; fn < 4; ++fn) {
      int n = n0 + wn * 64 + fn * 16 + l16;
      float bb = bg[e * DFF + n];
#pragma unroll
      for (int r = 0; r < 4; ++r) {
        int m = mb + fm * 16 + quad * 4 + r;
        if (m < count) {
          float v = acc[fm][fn][r] + bb;
          S[(size_t)(base + m) * DFF + n] = (bf16)(v / (1.f + __expf(-v)));
        }
      }
    }
  }
}

// ---------------- stage 3: Y = S@w3 + b3  [128m x 64n] ----------------
__global__ __launch_bounds__(256) void ffn3_kernel(
    const bf16* __restrict__ S, const bf16* __restrict__ w3t,
    const float* __restrict__ b3, const int* __restrict__ off,
    bf16* __restrict__ Y) {
  int e = blockIdx.y;
  int base = off[e];
  int count = off[e + 1] - base;
  int m0 = blockIdx.z * 128;
  if (m0 >= count) return;
  int n0 = blockIdx.x * 64;

  __shared__ __align__(16) bf16 As[128 * 64];   // 16 KB
  __shared__ __align__(16) bf16 Bs[64 * 64];    // 8 KB

  int tid = threadIdx.x;
  int wave = tid >> 6, lane = tid & 63;
  int quad = lane >> 4, l16 = lane & 15;
  int wm = wave & 1, wn = wave >> 1;
  int lr = lane >> 3, lc = lane & 7;
  int cg = (lc ^ lr) * 16;

  const char* apj[4];
#pragma unroll
  for (int j = 0; j < 4; ++j) {
    int r = m0 + wave * 32 + j * 8 + lr;
    if (r >= count) r = count - 1;
    apj[j] = (const char*)(S + (size_t)(base + r) * DFF) + cg;
  }
  const char* we = (const char*)(w3t + (size_t)e * H * DFF);
  const char* bpj[2];
#pragma unroll
  for (int j = 0; j < 2; ++j) {
    int r = n0 + wave * 16 + j * 8 + lr;
    bpj[j] = we + (size_t)r * (DFF * 2) + cg;
  }

  char* asd = (char*)As + wave * 4096;
  char* bsd = (char*)Bs + wave * 2048;

  int slot0 = ((0 + quad) ^ (l16 & 7)) * 16;
  int slot1 = ((4 + quad) ^ (l16 & 7)) * 16;
  const char* arp = (const char*)As + (wm * 64 + l16) * 128;
  const char* brp = (const char*)Bs + (wn * 32 + l16) * 128;

  f32x4 acc[4][2] = {};

  for (int k0 = 0; k0 < DFF * 2; k0 += 128) {
#pragma unroll
    for (int j = 0; j < 4; ++j) async_copy16(apj[j] + k0, asd + j * 1024);
#pragma unroll
    for (int j = 0; j < 2; ++j) async_copy16(bpj[j] + k0, bsd + j * 1024);
    __syncthreads();
#pragma unroll
    for (int ks = 0; ks < 2; ++ks) {
      int slot = ks ? slot1 : slot0;
      bf16x8 af[4], bfr[2];
#pragma unroll
      for (int i = 0; i < 4; ++i) af[i] = *(const bf16x8*)(arp + i * 2048 + slot);
#pragma unroll
      for (int i = 0; i < 2; ++i) bfr[i] = *(const bf16x8*)(brp + i * 2048 + slot);
#pragma unroll
      for (int fm = 0; fm < 4; ++fm)
#pragma unroll
        for (int fn = 0; fn < 2; ++fn)
          acc[fm][fn] = __builtin_amdgcn_mfma_f32_16x16x32_bf16(af[fm], bfr[fn], acc[fm][fn], 0, 0, 0);
    }
    __syncthreads();
  }

  int mb = m0 + wm * 64;
#pragma unroll
  for (int fm = 0; fm < 4; ++fm) {
#pragma unroll
    for (int fn = 0; fn < 2; ++fn) {
      int n = n0 + wn * 32 + fn * 16 + l16;
      float bb = b3[e * H + n];
#pragma unroll
      for (int r = 0; r < 4; ++r) {
        int m = mb + fm * 16 + quad * 4 + r;
        if (m < count) {
          Y[(size_t)(base + m) * H + n] = (bf16)(acc[fm][fn][r] + bb);
        }
      }
    }
  }
}

// ---------------- combine: out[t] = w0*Y[p0] + w1*Y[p1] ----------------
__global__ __launch_bounds__(256) void combine_kernel(
    const bf16* __restrict__ Y, const int* __restrict__ pair_pos,
    const float* __restrict__ topw, float* __restrict__ out) {
  int idx = blockIdx.x * 256 + threadIdx.x;   // one float4 per thread
  int t = idx >> 8;                           // H/4 = 256 float4 per token
  int h4 = idx & 255;
  int p0 = pair_pos[2 * t], p1 = pair_pos[2 * t + 1];
  float w0 = topw[2 * t], w1 = topw[2 * t + 1];
  bf16x4 a = *(const bf16x4*)(Y + (size_t)p0 * H + h4 * 4);
  bf16x4 b = *(const bf16x4*)(Y + (size_t)p1 * H + h4 * 4);
  float4 o;
  o.x = w0 * (float)a[0] + w1 * (float)b[0];
  o.y = w0 * (float)a[1] + w1 * (float)b[1];
  o.z = w0 * (float)a[2] + w1 * (float)b[2];
  o.w = w0 * (float)a[3] + w1 * (float)b[3];
  ((float4*)out)[idx] = o;
}

extern "C" void kernel_launch(void* const* d_in, const int* in_sizes, int n_in,
                              void* d_out, int out_size, void* d_ws, size_t ws_size,
                              hipStream_t stream) {
  const float* x  = (const float*)d_in[0];
  const float* gw = (const float*)d_in[1];
  const float* gb = (const float*)d_in[2];
  const float* w1 = (const float*)d_in[3];
  const float* b1 = (const float*)d_in[4];
  const float* w2 = (const float*)d_in[5];
  const float* b2 = (const float*)d_in[6];
  const float* wg = (const float*)d_in[7];
  const float* bg = (const float*)d_in[8];
  const float* w3 = (const float*)d_in[9];
  const float* b3 = (const float*)d_in[10];
  float* out = (float*)d_out;

  char* ws = (char*)d_ws;
  int* cnt      = (int*)(ws + 0);
  int* cnt2     = (int*)(ws + 64);
  int* off      = (int*)(ws + 128);
  int* topi     = (int*)(ws + 4096);
  float* topw   = (float*)(ws + 4096 + 16384);
  int* pair_tok = (int*)(ws + 4096 + 16384 * 2);
  int* pair_pos = (int*)(ws + 4096 + 16384 * 3);

  const size_t MB = 1024 * 1024;
  char* big = ws + MB;
  bf16* xb  = (bf16*)(big);                 // 4 MB   [NT][H]
  bf16* w1t = (bf16*)(big + 4   * MB);      // 32 MB  [E][DFF][H]
  bf16* w2t = (bf16*)(big + 36  * MB);      // 32 MB  [E][DFF][H]
  bf16* wgt = (bf16*)(big + 68  * MB);      // 64 MB  [E][DFF][DFF]
  bf16* w3t = (bf16*)(big + 132 * MB);      // 32 MB  [E][H][DFF]
  bf16* Z   = (bf16*)(big + 164 * MB);      // 16 MB  [NPAIR][DFF]
  bf16* S   = (bf16*)(big + 180 * MB);      // 16 MB  [NPAIR][DFF]
  bf16* Y   = (bf16*)(big + 196 * MB);      // 8 MB   [NPAIR][H]

  hipMemsetAsync(d_ws, 0, 256, stream);  // cnt, cnt2, off
  gate_kernel<<<NT, 64, 0, stream>>>(x, gw, gb, cnt, topi, topw, xb);
  prefix_kernel<<<1, 64, 0, stream>>>(cnt, off);
  scatter_kernel<<<NT / 256, 256, 0, stream>>>(topi, cnt2, off, pair_tok, pair_pos);

  tconv_kernel<<<20480, 256, 0, stream>>>(w1, w2, wg, w3, w1t, w2t, wgt, w3t);

  ffn1_kernel<<<dim3(DFF / 64, NE, NPAIR / 128), 256, 0, stream>>>(xb, w1t, b1, w2t, b2, off, pair_tok, Z);
  ffn2_kernel<<<dim3(DFF / 128, NE, NPAIR / 128), 256, 0, stream>>>(Z, wgt, bg, off, S);
  ffn3_kernel<<<dim3(H / 64, NE, NPAIR / 128), 256, 0, stream>>>(S, w3t, b3, off, Y);
  combine_kernel<<<(NT * H / 4) / 256, 256, 0, stream>>>(Y, pair_pos, topw, out);
}